// Round 1
// baseline (488.879 us; speedup 1.0000x reference)
//
#include <hip/hip_runtime.h>
#include <hip/hip_bf16.h>

#define N_TOK   32768       // 8 * 4096 tokens
#define DPROJ   1024
#define SCALE   32.0f       // sqrt(1024)

// ---------------------------------------------------------------------------
// Kernel 1: bucketize tokens. perm[b][j] = original token position,
// rowidx[b][j] = row within emb table b. Order within bucket is arbitrary
// (atomic), but output values are order-independent.
// ---------------------------------------------------------------------------
__global__ void k_bucketize(const int* __restrict__ inp, int* __restrict__ cnt,
                            int* __restrict__ perm, int* __restrict__ rowidx) {
    int i = blockIdx.x * blockDim.x + threadIdx.x;
    if (i >= N_TOK) return;
    int t = inp[i];
    int b, l;
    if (t < 20000)       { b = 0; l = 0; }
    else if (t < 40000)  { b = 1; l = 20000; }
    else if (t < 200000) { b = 2; l = 40000; }
    else                 { b = 3; l = 200000; }
    int pos = atomicAdd(&cnt[b], 1);
    perm[b * N_TOK + pos]   = i;
    rowidx[b * N_TOK + pos] = t - l;
}

// ---------------------------------------------------------------------------
// Kernel 2: 64-aligned prefix of bucket counts -> each 64-row tile of the
// global padded position space belongs to exactly one bucket.
// ---------------------------------------------------------------------------
__global__ void k_prefix(const int* __restrict__ cnt, int* __restrict__ base) {
    if (threadIdx.x == 0) {
        int acc = 0;
        base[0] = 0;
        for (int b = 0; b < 4; ++b) {
            acc = (acc + cnt[b] + 63) & ~63;
            base[b + 1] = acc;
        }
    }
}

// ---------------------------------------------------------------------------
// Kernel 3: fused gathered GEMM over all buckets.
// Tile: BM=64 x BN=128, BK=16, 256 threads, 8x4 micro-tile per thread.
// K-loop: 32 FMA per kk vs 3 ds_read_b128 -> VALU-bound.
// ---------------------------------------------------------------------------
__global__ __launch_bounds__(256, 2) void k_gemm(
    const float* __restrict__ emb0, const float* __restrict__ emb1,
    const float* __restrict__ emb2, const float* __restrict__ emb3,
    const float* __restrict__ proj0, const float* __restrict__ proj1,
    const float* __restrict__ proj2, const float* __restrict__ proj3,
    const int* __restrict__ cnt, const int* __restrict__ base,
    const int* __restrict__ perm, const int* __restrict__ rowidx,
    float* __restrict__ out)
{
    __shared__ float As[16][64];    // [k][m], 4 KB
    __shared__ float Bs[16][128];   // [k][n], 8 KB

    const int p0 = blockIdx.x * 64;
    if (p0 >= base[4]) return;                      // past padded total
    int b;
    if      (p0 >= base[3]) b = 3;
    else if (p0 >= base[2]) b = 2;
    else if (p0 >= base[1]) b = 1;
    else                    b = 0;
    const int M  = cnt[b];
    const int m0 = p0 - base[b];
    if (m0 >= M) return;                            // padding-only tile

    const float* emb; const float* proj; int K;
    switch (b) {
        case 0:  emb = emb0; proj = proj0; K = 1024; break;
        case 1:  emb = emb1; proj = proj1; K = 256;  break;
        case 2:  emb = emb2; proj = proj2; K = 64;   break;
        default: emb = emb3; proj = proj3; K = 16;   break;
    }
    const int* pperm = perm   + b * N_TOK;
    const int* prow  = rowidx + b * N_TOK;

    const int tid = threadIdx.x;
    const int n0  = blockIdx.y * 128;
    const int tr  = tid >> 5;         // 0..7  (row group)
    const int tc  = tid & 31;         // 0..31 (col group)

    // A staging mapping: 64 rows x 16 k, one float4 per thread
    const int ar = tid >> 2;          // 0..63
    const int ac = (tid & 3) << 2;    // 0,4,8,12
    const bool avalid = (m0 + ar) < M;
    const int  arow   = avalid ? prow[m0 + ar] : 0;
    const float* aptr = emb + (size_t)arow * K + ac;

    float acc[8][4];
    #pragma unroll
    for (int r = 0; r < 8; ++r)
        #pragma unroll
        for (int j = 0; j < 4; ++j) acc[r][j] = 0.0f;

    for (int k0 = 0; k0 < K; k0 += 16) {
        // global loads first (overlap with previous compute)
        float4 a4 = make_float4(0.f, 0.f, 0.f, 0.f);
        if (avalid) a4 = *reinterpret_cast<const float4*>(aptr + k0);
        float4 bsv[2];
        #pragma unroll
        for (int i = 0; i < 2; ++i) {
            int idx = tid + i * 256;            // 0..511 float4 slots
            int br  = idx >> 5;                 // 0..15
            int bc  = (idx & 31) << 2;          // 0..124
            bsv[i] = *reinterpret_cast<const float4*>(
                proj + (size_t)(k0 + br) * DPROJ + n0 + bc);
        }
        __syncthreads();                        // previous tile reads done
        As[ac + 0][ar] = a4.x; As[ac + 1][ar] = a4.y;
        As[ac + 2][ar] = a4.z; As[ac + 3][ar] = a4.w;
        #pragma unroll
        for (int i = 0; i < 2; ++i) {
            int idx = tid + i * 256;
            int br  = idx >> 5;
            int bc  = (idx & 31) << 2;
            *reinterpret_cast<float4*>(&Bs[br][bc]) = bsv[i];
        }
        __syncthreads();

        #pragma unroll
        for (int kk = 0; kk < 16; ++kk) {
            float a[8], bb[4];
            *reinterpret_cast<float4*>(&a[0]) =
                *reinterpret_cast<const float4*>(&As[kk][tr * 8]);
            *reinterpret_cast<float4*>(&a[4]) =
                *reinterpret_cast<const float4*>(&As[kk][tr * 8 + 4]);
            *reinterpret_cast<float4*>(&bb[0]) =
                *reinterpret_cast<const float4*>(&Bs[kk][tc * 4]);
            #pragma unroll
            for (int r = 0; r < 8; ++r)
                #pragma unroll
                for (int j = 0; j < 4; ++j)
                    acc[r][j] = fmaf(a[r], bb[j], acc[r][j]);
        }
    }

    #pragma unroll
    for (int r = 0; r < 8; ++r) {
        int m = m0 + tr * 8 + r;
        if (m < M) {
            float4 v;
            v.x = acc[r][0] * SCALE; v.y = acc[r][1] * SCALE;
            v.z = acc[r][2] * SCALE; v.w = acc[r][3] * SCALE;
            *reinterpret_cast<float4*>(
                out + (size_t)pperm[m] * DPROJ + n0 + tc * 4) = v;
        }
    }
}

// ---------------------------------------------------------------------------
// Fallback (ws too small): one block per token, direct fp32 dot products.
// Slow but correct.
// ---------------------------------------------------------------------------
__global__ void k_naive(const int* __restrict__ inp,
                        const float* __restrict__ emb0, const float* __restrict__ emb1,
                        const float* __restrict__ emb2, const float* __restrict__ emb3,
                        const float* __restrict__ proj0, const float* __restrict__ proj1,
                        const float* __restrict__ proj2, const float* __restrict__ proj3,
                        float* __restrict__ out)
{
    __shared__ float e[1024];
    int t = inp[blockIdx.x];
    const float* emb; const float* proj; int K, l;
    if (t < 20000)       { emb = emb0; proj = proj0; K = 1024; l = 0; }
    else if (t < 40000)  { emb = emb1; proj = proj1; K = 256;  l = 20000; }
    else if (t < 200000) { emb = emb2; proj = proj2; K = 64;   l = 40000; }
    else                 { emb = emb3; proj = proj3; K = 16;   l = 200000; }
    int tid = threadIdx.x;
    for (int k = tid; k < K; k += 256) e[k] = emb[(size_t)(t - l) * K + k];
    __syncthreads();
    float acc[4] = {0.f, 0.f, 0.f, 0.f};
    for (int k = 0; k < K; ++k) {
        float ek = e[k];
        #pragma unroll
        for (int c = 0; c < 4; ++c)
            acc[c] = fmaf(ek, proj[(size_t)k * DPROJ + tid + 256 * c], acc[c]);
    }
    #pragma unroll
    for (int c = 0; c < 4; ++c)
        out[(size_t)blockIdx.x * DPROJ + tid + 256 * c] = acc[c] * SCALE;
}

extern "C" void kernel_launch(void* const* d_in, const int* in_sizes, int n_in,
                              void* d_out, int out_size, void* d_ws, size_t ws_size,
                              hipStream_t stream) {
    // setup_inputs dict order: inp, emb0, proj0, emb1, proj1, emb2, proj2, emb3, proj3
    const int*   inp   = (const int*)d_in[0];
    const float* emb0  = (const float*)d_in[1];
    const float* proj0 = (const float*)d_in[2];
    const float* emb1  = (const float*)d_in[3];
    const float* proj1 = (const float*)d_in[4];
    const float* emb2  = (const float*)d_in[5];
    const float* proj2 = (const float*)d_in[6];
    const float* emb3  = (const float*)d_in[7];
    const float* proj3 = (const float*)d_in[8];
    float* out = (float*)d_out;

    const size_t needed = 64 + 2ull * 4 * N_TOK * 4;   // cnt/base + perm + rowidx
    if (d_ws == nullptr || ws_size < needed) {
        k_naive<<<N_TOK, 256, 0, stream>>>(inp, emb0, emb1, emb2, emb3,
                                           proj0, proj1, proj2, proj3, out);
        return;
    }

    int* cnt    = (int*)d_ws;                       // 4 ints
    int* base   = (int*)d_ws + 4;                   // 5 ints
    int* perm   = (int*)((char*)d_ws + 64);         // 4 * N_TOK ints
    int* rowidx = perm + 4 * N_TOK;                 // 4 * N_TOK ints

    hipMemsetAsync(cnt, 0, 16, stream);             // must re-zero every call
    k_bucketize<<<(N_TOK + 255) / 256, 256, 0, stream>>>(inp, cnt, perm, rowidx);
    k_prefix<<<1, 64, 0, stream>>>(cnt, base);

    dim3 grid(516, 8);   // 516 = ceil((32768 + 4*63)/64) worst-case padded tiles
    k_gemm<<<grid, 256, 0, stream>>>(emb0, emb1, emb2, emb3,
                                     proj0, proj1, proj2, proj3,
                                     cnt, base, perm, rowidx, out);
}

// Round 3
// 86.744 us; speedup vs baseline: 5.6359x; 5.6359x over previous
//
#include <hip/hip_runtime.h>
#include <hip/hip_bf16.h>

#define N_TOK   32768       // 8 * 4096 tokens
#define DPROJ   1024
#define SCALE   32.0f       // sqrt(1024)

typedef short bf16x8 __attribute__((ext_vector_type(8)));
typedef float f32x4  __attribute__((ext_vector_type(4)));

__device__ __forceinline__ short f2bf(float f) {
    unsigned u = __builtin_bit_cast(unsigned, f);
    unsigned r = (u + 0x7FFFu + ((u >> 16) & 1u)) >> 16;   // RNE
    return (short)r;
}

// ---------------------------------------------------------------------------
// Kernel 1: bucketize with per-wave ballot aggregation (4 atomics per wave).
// ---------------------------------------------------------------------------
__global__ void k_bucketize(const int* __restrict__ inp, int* __restrict__ cnt,
                            int* __restrict__ perm, int* __restrict__ rowidx) {
    int i = blockIdx.x * blockDim.x + threadIdx.x;     // N_TOK % 256 == 0
    int t = inp[i];
    int b, l;
    if (t < 20000)       { b = 0; l = 0; }
    else if (t < 40000)  { b = 1; l = 20000; }
    else if (t < 200000) { b = 2; l = 40000; }
    else                 { b = 3; l = 200000; }

    unsigned long long m0 = __ballot(b == 0);
    unsigned long long m1 = __ballot(b == 1);
    unsigned long long m2 = __ballot(b == 2);
    unsigned long long m3 = __ballot(b == 3);

    int lane = threadIdx.x & 63;
    int mybase = 0;
    if (lane < 4) {
        unsigned long long mm = (lane == 0) ? m0 : (lane == 1) ? m1 : (lane == 2) ? m2 : m3;
        mybase = atomicAdd(&cnt[lane], __popcll(mm));
    }
    int base = __shfl(mybase, b);
    unsigned long long mine = (b == 0) ? m0 : (b == 1) ? m1 : (b == 2) ? m2 : m3;
    unsigned long long lt = (lane == 0) ? 0ull : (~0ull >> (64 - lane));
    int pos = base + __popcll(mine & lt);
    perm[b * N_TOK + pos]   = i;
    rowidx[b * N_TOK + pos] = t - l;
}

// ---------------------------------------------------------------------------
// Kernel 2: transpose + convert proj tables -> projT[n][k] bf16 in ws.
// Tile: 16 n x 128 k. Coalesced read and write.
// ---------------------------------------------------------------------------
__global__ void k_transpose(const float* __restrict__ p0, const float* __restrict__ p1,
                            const float* __restrict__ p2, const float* __restrict__ p3,
                            short* __restrict__ t0, short* __restrict__ t1,
                            short* __restrict__ t2, short* __restrict__ t3) {
    __shared__ float tile[128][17];
    int bid = blockIdx.x;
    const float* src; short* dst; int K; int rel;
    if (bid < 512)      { src = p0; dst = t0; K = 1024; rel = bid; }
    else if (bid < 640) { src = p1; dst = t1; K = 256;  rel = bid - 512; }
    else if (bid < 704) { src = p2; dst = t2; K = 64;   rel = bid - 640; }
    else                { src = p3; dst = t3; K = 16;   rel = bid - 704; }
    int ktiles = (K + 127) >> 7;
    int k0 = (rel % ktiles) * 128;
    int n0 = (rel / ktiles) * 16;
    int t = threadIdx.x;

    #pragma unroll
    for (int i = 0; i < 2; ++i) {
        int idx = t + i * 256;          // 0..511
        int k = idx >> 2;               // 0..127
        int nc = (idx & 3) * 4;         // 0,4,8,12
        if (k0 + k < K) {
            float4 v = *reinterpret_cast<const float4*>(src + (size_t)(k0 + k) * DPROJ + n0 + nc);
            tile[k][nc + 0] = v.x; tile[k][nc + 1] = v.y;
            tile[k][nc + 2] = v.z; tile[k][nc + 3] = v.w;
        }
    }
    __syncthreads();
    int n  = t >> 4;                    // 0..15
    int kc = (t & 15) * 8;              // 0..120
    if (k0 + kc < K) {
        short s[8];
        #pragma unroll
        for (int j = 0; j < 8; ++j) s[j] = f2bf(tile[kc + j][n]);
        *reinterpret_cast<int4*>(dst + (size_t)(n0 + n) * K + k0 + kc) =
            *reinterpret_cast<const int4*>(s);
    }
}

// ---------------------------------------------------------------------------
// Kernel 3: fused gathered bf16-MFMA GEMM over all buckets.
// BM=64, BN=128, BK=32; 4 waves, each wave: 64 rows x 32 cols (4x2 frags).
// ---------------------------------------------------------------------------
__global__ __launch_bounds__(256, 4) void k_gemm(
    const float* __restrict__ e0, const float* __restrict__ e1,
    const float* __restrict__ e2, const float* __restrict__ e3,
    const short* __restrict__ t0, const short* __restrict__ t1,
    const short* __restrict__ t2, const short* __restrict__ t3,
    const int* __restrict__ cnt, const int* __restrict__ perm,
    const int* __restrict__ rowidx, float* __restrict__ out)
{
    __shared__ short As[64][40];    // stride 80B: frag b128 reads hit all 32 banks
    __shared__ short Bs[128][40];

    const int c0 = cnt[0], c1 = cnt[1], c2 = cnt[2], c3 = cnt[3];
    const int q0 = (c0 + 63) & ~63;
    const int q1 = q0 + ((c1 + 63) & ~63);
    const int q2 = q1 + ((c2 + 63) & ~63);
    const int q3 = q2 + ((c3 + 63) & ~63);
    const int p0 = blockIdx.x * 64;
    if (p0 >= q3) return;
    int b, M, m0, K; const float* emb; const short* bt;
    if (p0 < q0)      { b = 0; M = c0; m0 = p0;      K = 1024; emb = e0; bt = t0; }
    else if (p0 < q1) { b = 1; M = c1; m0 = p0 - q0; K = 256;  emb = e1; bt = t1; }
    else if (p0 < q2) { b = 2; M = c2; m0 = p0 - q1; K = 64;   emb = e2; bt = t2; }
    else              { b = 3; M = c3; m0 = p0 - q2; K = 16;   emb = e3; bt = t3; }
    if (m0 >= M) return;
    const int* pperm = perm   + b * N_TOK;
    const int* prow  = rowidx + b * N_TOK;

    const int tid  = threadIdx.x;
    const int lane = tid & 63;
    const int w    = tid >> 6;
    const int n0   = blockIdx.y * 128;

    // staging indices: thread -> (row, 8-elem chunk)
    const int ar = tid >> 2;            // 0..63
    const int ac = (tid & 3) * 8;       // 0,8,16,24
    const bool avalid = (m0 + ar) < M;
    const int  arow   = avalid ? prow[m0 + ar] : 0;
    const float* aptr = emb + (size_t)arow * K;

    f32x4 acc[4][2];
    #pragma unroll
    for (int mi = 0; mi < 4; ++mi)
        #pragma unroll
        for (int ni = 0; ni < 2; ++ni) acc[mi][ni] = (f32x4)0.0f;

    const int koff = (lane >> 4) * 8;   // same k-bijection for A and B frags
    const int fr   = lane & 15;

    for (int k0 = 0; k0 < K; k0 += 32) {
        // ---- global loads first (overlap with previous tile's MFMA) ----
        float av[8];
        #pragma unroll
        for (int j = 0; j < 8; ++j) av[j] = 0.0f;
        if (avalid && (k0 + ac) < K) {
            float4 x = *reinterpret_cast<const float4*>(aptr + k0 + ac);
            float4 y = *reinterpret_cast<const float4*>(aptr + k0 + ac + 4);
            av[0] = x.x; av[1] = x.y; av[2] = x.z; av[3] = x.w;
            av[4] = y.x; av[5] = y.y; av[6] = y.z; av[7] = y.w;
        }
        short bv[2][8];
        #pragma unroll
        for (int g = 0; g < 2; ++g) {
            int bn = g * 64 + (tid >> 2);       // 0..127
            int bq = (tid & 3) * 8;             // 0,8,16,24
            if ((k0 + bq) < K) {
                *reinterpret_cast<int4*>(&bv[g][0]) =
                    *reinterpret_cast<const int4*>(bt + (size_t)(n0 + bn) * K + k0 + bq);
            } else {
                #pragma unroll
                for (int j = 0; j < 8; ++j) bv[g][j] = 0;
            }
        }
        __syncthreads();                        // previous tile's frag reads done
        {
            short asv[8];
            #pragma unroll
            for (int j = 0; j < 8; ++j) asv[j] = f2bf(av[j]);
            *reinterpret_cast<int4*>(&As[ar][ac]) = *reinterpret_cast<const int4*>(asv);
            #pragma unroll
            for (int g = 0; g < 2; ++g)
                *reinterpret_cast<int4*>(&Bs[g * 64 + (tid >> 2)][(tid & 3) * 8]) =
                    *reinterpret_cast<const int4*>(&bv[g][0]);
        }
        __syncthreads();

        bf16x8 afr[4], bfr[2];
        #pragma unroll
        for (int mi = 0; mi < 4; ++mi)
            afr[mi] = *reinterpret_cast<const bf16x8*>(&As[mi * 16 + fr][koff]);
        #pragma unroll
        for (int ni = 0; ni < 2; ++ni)
            bfr[ni] = *reinterpret_cast<const bf16x8*>(&Bs[w * 32 + ni * 16 + fr][koff]);
        #pragma unroll
        for (int mi = 0; mi < 4; ++mi)
            #pragma unroll
            for (int ni = 0; ni < 2; ++ni)
                acc[mi][ni] = __builtin_amdgcn_mfma_f32_16x16x32_bf16(
                    afr[mi], bfr[ni], acc[mi][ni], 0, 0, 0);
    }

    // ---- epilogue: C/D layout col=lane&15, row=(lane>>4)*4+reg ----
    const int colb = n0 + w * 32 + fr;
    const int rowg = (lane >> 4) * 4;
    #pragma unroll
    for (int mi = 0; mi < 4; ++mi) {
        #pragma unroll
        for (int j = 0; j < 4; ++j) {
            int m = m0 + mi * 16 + rowg + j;
            if (m < M) {
                size_t r = (size_t)pperm[m] * DPROJ + colb;
                out[r]      = acc[mi][0][j] * SCALE;
                out[r + 16] = acc[mi][1][j] * SCALE;
            }
        }
    }
}

// ---------------------------------------------------------------------------
// Fallback (ws too small): one block per token, direct fp32 dot products.
// ---------------------------------------------------------------------------
__global__ void k_naive(const int* __restrict__ inp,
                        const float* __restrict__ emb0, const float* __restrict__ emb1,
                        const float* __restrict__ emb2, const float* __restrict__ emb3,
                        const float* __restrict__ proj0, const float* __restrict__ proj1,
                        const float* __restrict__ proj2, const float* __restrict__ proj3,
                        float* __restrict__ out)
{
    __shared__ float e[1024];
    int t = inp[blockIdx.x];
    const float* emb; const float* proj; int K, l;
    if (t < 20000)       { emb = emb0; proj = proj0; K = 1024; l = 0; }
    else if (t < 40000)  { emb = emb1; proj = proj1; K = 256;  l = 20000; }
    else if (t < 200000) { emb = emb2; proj = proj2; K = 64;   l = 40000; }
    else                 { emb = emb3; proj = proj3; K = 16;   l = 200000; }
    int tid = threadIdx.x;
    for (int k = tid; k < K; k += 256) e[k] = emb[(size_t)(t - l) * K + k];
    __syncthreads();
    float acc[4] = {0.f, 0.f, 0.f, 0.f};
    for (int k = 0; k < K; ++k) {
        float ek = e[k];
        #pragma unroll
        for (int c = 0; c < 4; ++c)
            acc[c] = fmaf(ek, proj[(size_t)k * DPROJ + tid + 256 * c], acc[c]);
    }
    #pragma unroll
    for (int c = 0; c < 4; ++c)
        out[(size_t)blockIdx.x * DPROJ + tid + 256 * c] = acc[c] * SCALE;
}

extern "C" void kernel_launch(void* const* d_in, const int* in_sizes, int n_in,
                              void* d_out, int out_size, void* d_ws, size_t ws_size,
                              hipStream_t stream) {
    const int*   inp   = (const int*)d_in[0];
    const float* emb0  = (const float*)d_in[1];
    const float* proj0 = (const float*)d_in[2];
    const float* emb1  = (const float*)d_in[3];
    const float* proj1 = (const float*)d_in[4];
    const float* emb2  = (const float*)d_in[5];
    const float* proj2 = (const float*)d_in[6];
    const float* emb3  = (const float*)d_in[7];
    const float* proj3 = (const float*)d_in[8];
    float* out = (float*)d_out;

    // ws layout (256B-aligned regions)
    const size_t off_cnt  = 0;
    const size_t off_perm = 256;
    const size_t off_row  = off_perm + 4ull * N_TOK * 4;          // 524288
    const size_t off_t0   = off_row  + 4ull * N_TOK * 4;
    const size_t off_t1   = off_t0 + 1024ull * 1024 * 2;
    const size_t off_t2   = off_t1 + 1024ull * 256 * 2;
    const size_t off_t3   = off_t2 + 1024ull * 64 * 2;
    const size_t needed   = off_t3 + 1024ull * 16 * 2;

    if (d_ws == nullptr || ws_size < needed) {
        k_naive<<<N_TOK, 256, 0, stream>>>(inp, emb0, emb1, emb2, emb3,
                                           proj0, proj1, proj2, proj3, out);
        return;
    }

    char* ws = (char*)d_ws;
    int*   cnt    = (int*)(ws + off_cnt);
    int*   perm   = (int*)(ws + off_perm);
    int*   rowidx = (int*)(ws + off_row);
    short* t0     = (short*)(ws + off_t0);
    short* t1     = (short*)(ws + off_t1);
    short* t2     = (short*)(ws + off_t2);
    short* t3     = (short*)(ws + off_t3);

    hipMemsetAsync(cnt, 0, 16, stream);
    k_bucketize<<<N_TOK / 256, 256, 0, stream>>>(inp, cnt, perm, rowidx);
    k_transpose<<<768, 256, 0, stream>>>(proj0, proj1, proj2, proj3, t0, t1, t2, t3);

    dim3 grid(516, 8);      // worst-case padded tiles x 8 n-panels
    k_gemm<<<grid, 256, 0, stream>>>(emb0, emb1, emb2, emb3,
                                     t0, t1, t2, t3,
                                     cnt, perm, rowidx, out);
}

// Round 4
// 62.816 us; speedup vs baseline: 7.7827x; 1.3809x over previous
//
#include <hip/hip_runtime.h>
#include <hip/hip_bf16.h>

#define N_TOK   32768       // 8 * 4096 tokens
#define DPROJ   1024
#define SCALE   32.0f       // sqrt(1024)

typedef short bf16x8 __attribute__((ext_vector_type(8)));
typedef float f32x4  __attribute__((ext_vector_type(4)));

__device__ __forceinline__ short f2bf(float f) {
    unsigned u = __builtin_bit_cast(unsigned, f);
    unsigned r = (u + 0x7FFFu + ((u >> 16) & 1u)) >> 16;   // RNE
    return (short)r;
}

// ---------------------------------------------------------------------------
// Fused prep kernel.
//   blocks [0,128):   bucketize (wave-ballot aggregated, 4 atomics per wave)
//   blocks [128,896): transpose+convert proj -> projT[n][k] bf16
// The two jobs are independent; fusing them into one launch lets them run
// concurrently instead of serializing on the stream.
// ---------------------------------------------------------------------------
__global__ void k_prep(const int* __restrict__ inp, int* __restrict__ cnt,
                       int* __restrict__ perm, int* __restrict__ rowidx,
                       const float* __restrict__ p0, const float* __restrict__ p1,
                       const float* __restrict__ p2, const float* __restrict__ p3,
                       short* __restrict__ t0, short* __restrict__ t1,
                       short* __restrict__ t2, short* __restrict__ t3)
{
    __shared__ float tile[128][17];

    if (blockIdx.x < 128) {
        // ---------------- bucketize ----------------
        int i = blockIdx.x * 256 + threadIdx.x;
        int t = inp[i];
        int b, l;
        if (t < 20000)       { b = 0; l = 0; }
        else if (t < 40000)  { b = 1; l = 20000; }
        else if (t < 200000) { b = 2; l = 40000; }
        else                 { b = 3; l = 200000; }

        unsigned long long m0 = __ballot(b == 0);
        unsigned long long m1 = __ballot(b == 1);
        unsigned long long m2 = __ballot(b == 2);
        unsigned long long m3 = __ballot(b == 3);

        int lane = threadIdx.x & 63;
        int mybase = 0;
        if (lane < 4) {
            unsigned long long mm = (lane == 0) ? m0 : (lane == 1) ? m1 : (lane == 2) ? m2 : m3;
            mybase = atomicAdd(&cnt[lane], __popcll(mm));
        }
        int base = __shfl(mybase, b);
        unsigned long long mine = (b == 0) ? m0 : (b == 1) ? m1 : (b == 2) ? m2 : m3;
        unsigned long long lt = (lane == 0) ? 0ull : (~0ull >> (64 - lane));
        int pos = base + __popcll(mine & lt);
        perm[b * N_TOK + pos]   = i;
        rowidx[b * N_TOK + pos] = t - l;
        return;
    }

    // ---------------- transpose ----------------
    int bid = blockIdx.x - 128;
    const float* src; short* dst; int K; int rel;
    if (bid < 512)      { src = p0; dst = t0; K = 1024; rel = bid; }
    else if (bid < 640) { src = p1; dst = t1; K = 256;  rel = bid - 512; }
    else if (bid < 704) { src = p2; dst = t2; K = 64;   rel = bid - 640; }
    else                { src = p3; dst = t3; K = 16;   rel = bid - 704; }
    int ktiles = (K + 127) >> 7;
    int k0 = (rel % ktiles) * 128;
    int n0 = (rel / ktiles) * 16;
    int t = threadIdx.x;

    #pragma unroll
    for (int i = 0; i < 2; ++i) {
        int idx = t + i * 256;          // 0..511
        int k = idx >> 2;               // 0..127
        int nc = (idx & 3) * 4;         // 0,4,8,12
        if (k0 + k < K) {
            float4 v = *reinterpret_cast<const float4*>(src + (size_t)(k0 + k) * DPROJ + n0 + nc);
            tile[k][nc + 0] = v.x; tile[k][nc + 1] = v.y;
            tile[k][nc + 2] = v.z; tile[k][nc + 3] = v.w;
        }
    }
    __syncthreads();
    int n  = t >> 4;                    // 0..15
    int kc = (t & 15) * 8;              // 0..120
    if (k0 + kc < K) {
        short s[8];
        #pragma unroll
        for (int j = 0; j < 8; ++j) s[j] = f2bf(tile[kc + j][n]);
        *reinterpret_cast<int4*>(dst + (size_t)(n0 + n) * K + k0 + kc) =
            *reinterpret_cast<const int4*>(s);
    }
}

// ---------------------------------------------------------------------------
// Fused gathered bf16-MFMA GEMM over all buckets.
// BM=64, BN=256, BK=32; 4 waves, each wave: 64 rows x 64 cols (4x4 frags).
// grid(4, 516): x = n-panel -> the 4 blocks sharing one A-tile are adjacent
// in dispatch order, so A re-fetches hit L2/L3 instead of HBM.
// ---------------------------------------------------------------------------
__global__ __launch_bounds__(256, 2) void k_gemm(
    const float* __restrict__ e0, const float* __restrict__ e1,
    const float* __restrict__ e2, const float* __restrict__ e3,
    const short* __restrict__ t0, const short* __restrict__ t1,
    const short* __restrict__ t2, const short* __restrict__ t3,
    const int* __restrict__ cnt, const int* __restrict__ perm,
    const int* __restrict__ rowidx, float* __restrict__ out)
{
    __shared__ short As[64][40];    // stride 80B: b128 frag access is bank-uniform
    __shared__ short Bs[256][40];

    const int c0 = cnt[0], c1 = cnt[1], c2 = cnt[2], c3 = cnt[3];
    const int q0 = (c0 + 63) & ~63;
    const int q1 = q0 + ((c1 + 63) & ~63);
    const int q2 = q1 + ((c2 + 63) & ~63);
    const int q3 = q2 + ((c3 + 63) & ~63);
    const int p0 = blockIdx.y * 64;
    if (p0 >= q3) return;
    int b, M, m0, K; const float* emb; const short* bt;
    if (p0 < q0)      { b = 0; M = c0; m0 = p0;      K = 1024; emb = e0; bt = t0; }
    else if (p0 < q1) { b = 1; M = c1; m0 = p0 - q0; K = 256;  emb = e1; bt = t1; }
    else if (p0 < q2) { b = 2; M = c2; m0 = p0 - q1; K = 64;   emb = e2; bt = t2; }
    else              { b = 3; M = c3; m0 = p0 - q2; K = 16;   emb = e3; bt = t3; }
    if (m0 >= M) return;
    const int* pperm = perm   + b * N_TOK;
    const int* prow  = rowidx + b * N_TOK;

    const int tid  = threadIdx.x;
    const int lane = tid & 63;
    const int w    = tid >> 6;
    const int n0   = blockIdx.x * 256;

    // staging indices: thread -> (row, 8-elem chunk)
    const int ar = tid >> 2;            // 0..63
    const int ac = (tid & 3) * 8;       // 0,8,16,24
    const bool avalid = (m0 + ar) < M;
    const int  arow   = avalid ? prow[m0 + ar] : 0;
    const float* aptr = emb + (size_t)arow * K;

    f32x4 acc[4][4];
    #pragma unroll
    for (int mi = 0; mi < 4; ++mi)
        #pragma unroll
        for (int ni = 0; ni < 4; ++ni) acc[mi][ni] = (f32x4)0.0f;

    const int koff = (lane >> 4) * 8;   // same k-bijection for A and B frags
    const int fr   = lane & 15;

    for (int k0 = 0; k0 < K; k0 += 32) {
        // ---- global loads first (overlap with previous tile's MFMA) ----
        float av[8];
        #pragma unroll
        for (int j = 0; j < 8; ++j) av[j] = 0.0f;
        if (avalid && (k0 + ac) < K) {
            float4 x = *reinterpret_cast<const float4*>(aptr + k0 + ac);
            float4 y = *reinterpret_cast<const float4*>(aptr + k0 + ac + 4);
            av[0] = x.x; av[1] = x.y; av[2] = x.z; av[3] = x.w;
            av[4] = y.x; av[5] = y.y; av[6] = y.z; av[7] = y.w;
        }
        short bv[4][8];
        #pragma unroll
        for (int g = 0; g < 4; ++g) {
            int bn = g * 64 + (tid >> 2);       // 0..255
            int bq = (tid & 3) * 8;             // 0,8,16,24
            if ((k0 + bq) < K) {
                *reinterpret_cast<int4*>(&bv[g][0]) =
                    *reinterpret_cast<const int4*>(bt + (size_t)(n0 + bn) * K + k0 + bq);
            } else {
                #pragma unroll
                for (int j = 0; j < 8; ++j) bv[g][j] = 0;
            }
        }
        __syncthreads();                        // previous tile's frag reads done
        {
            short asv[8];
            #pragma unroll
            for (int j = 0; j < 8; ++j) asv[j] = f2bf(av[j]);
            *reinterpret_cast<int4*>(&As[ar][ac]) = *reinterpret_cast<const int4*>(asv);
            #pragma unroll
            for (int g = 0; g < 4; ++g)
                *reinterpret_cast<int4*>(&Bs[g * 64 + (tid >> 2)][(tid & 3) * 8]) =
                    *reinterpret_cast<const int4*>(&bv[g][0]);
        }
        __syncthreads();

        bf16x8 afr[4], bfr[4];
        #pragma unroll
        for (int mi = 0; mi < 4; ++mi)
            afr[mi] = *reinterpret_cast<const bf16x8*>(&As[mi * 16 + fr][koff]);
        #pragma unroll
        for (int ni = 0; ni < 4; ++ni)
            bfr[ni] = *reinterpret_cast<const bf16x8*>(&Bs[w * 64 + ni * 16 + fr][koff]);
        #pragma unroll
        for (int mi = 0; mi < 4; ++mi)
            #pragma unroll
            for (int ni = 0; ni < 4; ++ni)
                acc[mi][ni] = __builtin_amdgcn_mfma_f32_16x16x32_bf16(
                    afr[mi], bfr[ni], acc[mi][ni], 0, 0, 0);
    }

    // ---- epilogue: C/D layout col=lane&15, row=(lane>>4)*4+reg ----
    const int colb = n0 + w * 64 + fr;
    const int rowg = (lane >> 4) * 4;
    #pragma unroll
    for (int mi = 0; mi < 4; ++mi) {
        #pragma unroll
        for (int j = 0; j < 4; ++j) {
            int m = m0 + mi * 16 + rowg + j;
            if (m < M) {
                size_t r = (size_t)pperm[m] * DPROJ + colb;
                out[r]      = acc[mi][0][j] * SCALE;
                out[r + 16] = acc[mi][1][j] * SCALE;
                out[r + 32] = acc[mi][2][j] * SCALE;
                out[r + 48] = acc[mi][3][j] * SCALE;
            }
        }
    }
}

// ---------------------------------------------------------------------------
// Fallback (ws too small): one block per token, direct fp32 dot products.
// ---------------------------------------------------------------------------
__global__ void k_naive(const int* __restrict__ inp,
                        const float* __restrict__ emb0, const float* __restrict__ emb1,
                        const float* __restrict__ emb2, const float* __restrict__ emb3,
                        const float* __restrict__ proj0, const float* __restrict__ proj1,
                        const float* __restrict__ proj2, const float* __restrict__ proj3,
                        float* __restrict__ out)
{
    __shared__ float e[1024];
    int t = inp[blockIdx.x];
    const float* emb; const float* proj; int K, l;
    if (t < 20000)       { emb = emb0; proj = proj0; K = 1024; l = 0; }
    else if (t < 40000)  { emb = emb1; proj = proj1; K = 256;  l = 20000; }
    else if (t < 200000) { emb = emb2; proj = proj2; K = 64;   l = 40000; }
    else                 { emb = emb3; proj = proj3; K = 16;   l = 200000; }
    int tid = threadIdx.x;
    for (int k = tid; k < K; k += 256) e[k] = emb[(size_t)(t - l) * K + k];
    __syncthreads();
    float acc[4] = {0.f, 0.f, 0.f, 0.f};
    for (int k = 0; k < K; ++k) {
        float ek = e[k];
        #pragma unroll
        for (int c = 0; c < 4; ++c)
            acc[c] = fmaf(ek, proj[(size_t)k * DPROJ + tid + 256 * c], acc[c]);
    }
    #pragma unroll
    for (int c = 0; c < 4; ++c)
        out[(size_t)blockIdx.x * DPROJ + tid + 256 * c] = acc[c] * SCALE;
}

extern "C" void kernel_launch(void* const* d_in, const int* in_sizes, int n_in,
                              void* d_out, int out_size, void* d_ws, size_t ws_size,
                              hipStream_t stream) {
    const int*   inp   = (const int*)d_in[0];
    const float* emb0  = (const float*)d_in[1];
    const float* proj0 = (const float*)d_in[2];
    const float* emb1  = (const float*)d_in[3];
    const float* proj1 = (const float*)d_in[4];
    const float* emb2  = (const float*)d_in[5];
    const float* proj2 = (const float*)d_in[6];
    const float* emb3  = (const float*)d_in[7];
    const float* proj3 = (const float*)d_in[8];
    float* out = (float*)d_out;

    // ws layout (256B-aligned regions)
    const size_t off_cnt  = 0;
    const size_t off_perm = 256;
    const size_t off_row  = off_perm + 4ull * N_TOK * 4;          // 524288
    const size_t off_t0   = off_row  + 4ull * N_TOK * 4;
    const size_t off_t1   = off_t0 + 1024ull * 1024 * 2;
    const size_t off_t2   = off_t1 + 1024ull * 256 * 2;
    const size_t off_t3   = off_t2 + 1024ull * 64 * 2;
    const size_t needed   = off_t3 + 1024ull * 16 * 2;

    if (d_ws == nullptr || ws_size < needed) {
        k_naive<<<N_TOK, 256, 0, stream>>>(inp, emb0, emb1, emb2, emb3,
                                           proj0, proj1, proj2, proj3, out);
        return;
    }

    char* ws = (char*)d_ws;
    int*   cnt    = (int*)(ws + off_cnt);
    int*   perm   = (int*)(ws + off_perm);
    int*   rowidx = (int*)(ws + off_row);
    short* t0     = (short*)(ws + off_t0);
    short* t1     = (short*)(ws + off_t1);
    short* t2     = (short*)(ws + off_t2);
    short* t3     = (short*)(ws + off_t3);

    hipMemsetAsync(cnt, 0, 16, stream);
    k_prep<<<896, 256, 0, stream>>>(inp, cnt, perm, rowidx,
                                    proj0, proj1, proj2, proj3, t0, t1, t2, t3);

    dim3 grid(4, 516);      // x = n-panel (adjacent -> A-tile L2/L3 reuse)
    k_gemm<<<grid, 256, 0, stream>>>(emb0, emb1, emb2, emb3,
                                     t0, t1, t2, t3,
                                     cnt, perm, rowidx, out);
}